// Round 3
// baseline (255.362 us; speedup 1.0000x reference)
//
#include <hip/hip_runtime.h>
#include <cstddef>

// Problem constants (from reference)
#define BB 64
#define NN 207
#define KK 32
#define CC 8
#define DIN 64
#define DOUT 64
#define TILE 8               // n-positions per block
#define NT ((NN + TILE - 1) / TILE)   // 26 tiles along N
#define MPAD 68              // mean row stride: 68 floats -> phase-2 c-rows 4 banks apart

__device__ __forceinline__ float fast_tanh(float v) {
    // tanh(v) = 1 - 2/(exp(2v)+1); ~1e-6 rel err, saturates correctly.
    float e = __expf(2.0f * v);
    return 1.0f - 2.0f * __builtin_amdgcn_rcpf(e + 1.0f);
}

__global__ __launch_bounds__(256, 4) void ordered_gcn_kernel(
    const int* __restrict__ idx,      // [B, N, K]
    const float* __restrict__ x,      // [B, N, K, DIN]
    const float* __restrict__ W,      // [C, DOUT, DIN]
    float* __restrict__ out)          // [B, N, C, DOUT]
{
    __shared__ int   idx_s[TILE * KK];          // 1 KB
    __shared__ float inv_s[TILE * CC];          // 256 B
    __shared__ float mean_s[TILE * CC * MPAD];  // 17408 B

    const int tid = threadIdx.x;
    const int b  = blockIdx.y;
    const int n0 = blockIdx.x * TILE;

    // ---- load idx tile: one int per thread, coalesced ----
    {
        const int p = tid >> 5;
        const int k = tid & 31;
        const int n = n0 + p;
        idx_s[tid] = (n < NN) ? idx[((size_t)(b * NN + n)) * KK + k] : 0;
    }
    __syncthreads();

    // ---- per (pos, class) inverse clamped count (64 threads) ----
    if (tid < TILE * CC) {
        const int pp = tid >> 3, c = tid & 7;
        int cnt = 0;
        #pragma unroll
        for (int k = 0; k < KK; ++k) cnt += (idx_s[pp * KK + k] == c) ? 1 : 0;
        inv_s[tid] = 1.0f / (float)(cnt > 1 ? cnt : 1);
    }

    // ---- phase 1: class-bucketed float4 sums ----
    // thread = (p = tid>>5, d-quad = (tid&15)*4, k-parity kh = (tid>>4)&1).
    // Wave address pattern per iteration: 2 contiguous 512 B segments (one per pos).
    const int p  = tid >> 5;          // 0..7
    const int t5 = tid & 31;
    const int d4 = (t5 & 15) * 4;     // d offset, float4 aligned
    const int kh = t5 >> 4;           // k parity 0/1

    int n = n0 + p; if (n > NN - 1) n = NN - 1;   // clamp: garbage never stored
    const float* __restrict__ xp =
        x + (((size_t)(b * NN + n)) * KK + kh) * DIN + d4;

    float4 acc[CC];
    #pragma unroll
    for (int c = 0; c < CC; ++c) acc[c] = make_float4(0.f, 0.f, 0.f, 0.f);

    #pragma unroll 4
    for (int i = 0; i < 16; ++i) {
        const float4 v = *(const float4*)(xp + (size_t)(2 * i) * DIN); // k = kh + 2i
        const int ca = idx_s[p * KK + kh + 2 * i];
        #pragma unroll
        for (int cc = 0; cc < CC; ++cc) {
            const bool m = (ca == cc);
            acc[cc].x += m ? v.x : 0.0f;
            acc[cc].y += m ? v.y : 0.0f;
            acc[cc].z += m ? v.z : 0.0f;
            acc[cc].w += m ? v.w : 0.0f;
        }
    }

    // combine k-parity halves through mean_s: kh==1 writes partials, barrier,
    // kh==0 adds its partials, scales by inv count, writes the mean.
    if (kh == 1) {
        #pragma unroll
        for (int cc = 0; cc < CC; ++cc)
            *(float4*)(&mean_s[(p * CC + cc) * MPAD + d4]) = acc[cc];
    }
    __syncthreads();
    if (kh == 0) {
        #pragma unroll
        for (int cc = 0; cc < CC; ++cc) {
            float4 o = *(const float4*)(&mean_s[(p * CC + cc) * MPAD + d4]);
            const float s = inv_s[p * CC + cc];
            o.x = (o.x + acc[cc].x) * s;
            o.y = (o.y + acc[cc].y) * s;
            o.z = (o.z + acc[cc].z) * s;
            o.w = (o.w + acc[cc].w) * s;
            *(float4*)(&mean_s[(p * CC + cc) * MPAD + d4]) = o;
        }
    }
    __syncthreads();

    // ---- phase 2: out[p][c][o] = tanh(sum_d mean[p][c][d] * W[c][o][d]) ----
    // thread = (ph = tid>>7, c = (tid>>4)&7, o0 = (tid&15)*4); acc tile [4 pos][4 o].
    {
        const int ph = tid >> 7;
        const int c  = (tid >> 4) & 7;
        const int o0 = (tid & 15) * 4;
        float acc2[4][4];
        #pragma unroll
        for (int pp = 0; pp < 4; ++pp)
            #pragma unroll
            for (int j = 0; j < 4; ++j) acc2[pp][j] = 0.0f;

        const float* __restrict__ Wc = W + (size_t)c * DOUT * DIN;
        #pragma unroll 4
        for (int dd = 0; dd < DIN; dd += 4) {
            float4 w[4];
            #pragma unroll
            for (int j = 0; j < 4; ++j)
                w[j] = *(const float4*)(Wc + (size_t)(o0 + j) * DIN + dd);
            #pragma unroll
            for (int pp = 0; pp < 4; ++pp) {
                const int pq = ph * 4 + pp;
                const float4 m = *(const float4*)(&mean_s[(pq * CC + c) * MPAD + dd]);
                #pragma unroll
                for (int j = 0; j < 4; ++j) {
                    acc2[pp][j] = fmaf(m.x, w[j].x, acc2[pp][j]);
                    acc2[pp][j] = fmaf(m.y, w[j].y, acc2[pp][j]);
                    acc2[pp][j] = fmaf(m.z, w[j].z, acc2[pp][j]);
                    acc2[pp][j] = fmaf(m.w, w[j].w, acc2[pp][j]);
                }
            }
        }

        #pragma unroll
        for (int pp = 0; pp < 4; ++pp) {
            const int pq = ph * 4 + pp;
            const int nn = n0 + pq;
            if (nn < NN) {
                float4 r;
                r.x = fast_tanh(acc2[pp][0]);
                r.y = fast_tanh(acc2[pp][1]);
                r.z = fast_tanh(acc2[pp][2]);
                r.w = fast_tanh(acc2[pp][3]);
                *(float4*)(out + (((size_t)(b * NN + nn)) * CC + c) * DOUT + o0) = r;
            }
        }
    }
}

extern "C" void kernel_launch(void* const* d_in, const int* in_sizes, int n_in,
                              void* d_out, int out_size, void* d_ws, size_t ws_size,
                              hipStream_t stream) {
    const int*   idx = (const int*)d_in[0];    // clustered_index_topk [B,N,K] int32
    const float* x   = (const float*)d_in[1];  // weightedDinput_topk [B,N,K,DIN] f32
    const float* W   = (const float*)d_in[2];  // W [C,DOUT,DIN] f32
    float* out = (float*)d_out;                // [B,N,C,DOUT] f32

    dim3 grid(NT, BB);   // 26 x 64 = 1664 blocks
    dim3 block(256);
    ordered_gcn_kernel<<<grid, block, 0, stream>>>(idx, x, W, out);
}

// Round 4
// 184.380 us; speedup vs baseline: 1.3850x; 1.3850x over previous
//
#include <hip/hip_runtime.h>
#include <cstddef>

// Problem constants (from reference)
#define BB 64
#define NN 207
#define KK 32
#define CC 8
#define DIN 64
#define DOUT 64
#define TILE 16              // n-positions per block (16 halves W re-read traffic vs 8)
#define NT ((NN + TILE - 1) / TILE)   // 13 tiles along N
#define MPAD 68              // mean row stride: phase-2 class rows 4 banks apart

__device__ __forceinline__ float fast_tanh(float v) {
    // tanh(v) = 1 - 2/(exp(2v)+1); ~1e-6 rel err, saturates correctly.
    float e = __expf(2.0f * v);
    return 1.0f - 2.0f * __builtin_amdgcn_rcpf(e + 1.0f);
}

// ---- kernel 0: W[C][DOUT][DIN] -> Wt[C][DIN][DOUT] (one class per block) ----
__global__ __launch_bounds__(256) void transpose_W_kernel(
    const float* __restrict__ W, float* __restrict__ Wt)
{
    __shared__ float t[DIN * (DOUT + 1)];   // +1 pad: conflict-free transpose
    const int c   = blockIdx.x;
    const int tid = threadIdx.x;
    const float* __restrict__ Wc  = W  + (size_t)c * DOUT * DIN;
    float* __restrict__       Wtc = Wt + (size_t)c * DIN * DOUT;
    #pragma unroll
    for (int r = 0; r < 16; ++r) {
        const int i = r * 256 + tid;        // i = o*DIN + d  (coalesced read)
        const int o = i >> 6, d = i & 63;
        t[d * (DOUT + 1) + o] = Wc[i];
    }
    __syncthreads();
    #pragma unroll
    for (int r = 0; r < 16; ++r) {
        const int i = r * 256 + tid;        // i = d*DOUT + o (coalesced write)
        const int d = i >> 6, o = i & 63;
        Wtc[i] = t[d * (DOUT + 1) + o];
    }
}

// ---- main kernel ----
template<bool USE_WT>
__global__ __launch_bounds__(256, 4) void ordered_gcn_kernel(
    const int* __restrict__ idx,      // [B, N, K]
    const float* __restrict__ x,      // [B, N, K, DIN]
    const float* __restrict__ W,      // [C, DOUT, DIN]
    const float* __restrict__ Wt,     // [C, DIN, DOUT] (in d_ws)
    float* __restrict__ out)          // [B, N, C, DOUT]
{
    __shared__ int   idx_s[TILE * KK];          // 2 KB
    __shared__ float inv_s[TILE * CC];          // 512 B
    __shared__ float mean_s[TILE * CC * MPAD];  // 34816 B

    const int tid = threadIdx.x;
    const int b  = blockIdx.y;
    const int n0 = blockIdx.x * TILE;

    // ---- load idx tile: 512 ints, 2 per thread, coalesced ----
    #pragma unroll
    for (int r = 0; r < 2; ++r) {
        const int i = r * 256 + tid;
        const int p = i >> 5, k = i & 31;
        int n = n0 + p; if (n > NN - 1) n = NN - 1;   // clamped rows never stored
        idx_s[i] = idx[((size_t)(b * NN + n)) * KK + k];
    }
    __syncthreads();

    // ---- per (pos, class) inverse clamped count (128 threads) ----
    if (tid < TILE * CC) {
        const int pp = tid >> 3, c = tid & 7;
        int cnt = 0;
        #pragma unroll
        for (int k = 0; k < KK; ++k) cnt += (idx_s[pp * KK + k] == c) ? 1 : 0;
        inv_s[tid] = 1.0f / (float)(cnt > 1 ? cnt : 1);
    }
    // (inv_s is consumed only after the next barrier)

    // ---- phase 1: class-bucketed float4 sums, 8-deep load prefetch ----
    // thread = (p = tid>>4, d-quad = (tid&15)*4); covers all K=32 rows.
    // Wave pattern per load inst: 4 contiguous 256 B segments (16 lines) - minimal.
    const int p  = tid >> 4;          // 0..15
    const int d4 = (tid & 15) * 4;
    {
        int n = n0 + p; if (n > NN - 1) n = NN - 1;
        const float* __restrict__ xp = x + ((size_t)(b * NN + n)) * KK * DIN + d4;

        float4 acc[CC];
        #pragma unroll
        for (int c = 0; c < CC; ++c) acc[c] = make_float4(0.f, 0.f, 0.f, 0.f);

        #pragma unroll 1   // keep batches sequential: 8 loads in flight, no VGPR blowup
        for (int g = 0; g < 4; ++g) {
            float4 v[8];
            #pragma unroll
            for (int j = 0; j < 8; ++j)
                v[j] = *(const float4*)(xp + (size_t)(g * 8 + j) * DIN);
            #pragma unroll
            for (int j = 0; j < 8; ++j) {
                const int ca = idx_s[p * KK + g * 8 + j];
                #pragma unroll
                for (int cc_ = 0; cc_ < CC; ++cc_) {
                    const float mf = (ca == cc_) ? 1.0f : 0.0f;  // 1 sel + 4 fma per class
                    acc[cc_].x = fmaf(mf, v[j].x, acc[cc_].x);
                    acc[cc_].y = fmaf(mf, v[j].y, acc[cc_].y);
                    acc[cc_].z = fmaf(mf, v[j].z, acc[cc_].z);
                    acc[cc_].w = fmaf(mf, v[j].w, acc[cc_].w);
                }
            }
        }
        __syncthreads();   // inv_s ready for all threads

        #pragma unroll
        for (int cc_ = 0; cc_ < CC; ++cc_) {
            const float s = inv_s[p * CC + cc_];
            float4 m;
            m.x = acc[cc_].x * s; m.y = acc[cc_].y * s;
            m.z = acc[cc_].z * s; m.w = acc[cc_].w * s;
            *(float4*)(&mean_s[(p * CC + cc_) * MPAD + d4]) = m;
        }
    }
    __syncthreads();

    // ---- phase 2: out[p][c][o] = tanh(sum_d mean[p][c][d] * Wt[c][d][o]) ----
    // thread = (ph = tid>>7 -> pos 8ph..8ph+7, c = (tid>>4)&7, o0 = (tid&15)*4).
    // With Wt, each w-load is 256 B contiguous per 16-lane group (16 lines/inst
    // instead of 64 for the raw-W layout).
    {
        const int ph = tid >> 7;
        const int c  = (tid >> 4) & 7;
        const int o0 = (tid & 15) * 4;

        float4 acc2[8];
        #pragma unroll
        for (int pp = 0; pp < 8; ++pp) acc2[pp] = make_float4(0.f, 0.f, 0.f, 0.f);

        if (USE_WT) {
            const float* __restrict__ Wtc = Wt + (size_t)c * DIN * DOUT + o0;
            #pragma unroll 1
            for (int dc = 0; dc < 16; ++dc) {       // dd = dc*4
                const float4 w0 = *(const float4*)(Wtc + (size_t)(dc * 4 + 0) * DOUT);
                const float4 w1 = *(const float4*)(Wtc + (size_t)(dc * 4 + 1) * DOUT);
                const float4 w2 = *(const float4*)(Wtc + (size_t)(dc * 4 + 2) * DOUT);
                const float4 w3 = *(const float4*)(Wtc + (size_t)(dc * 4 + 3) * DOUT);
                #pragma unroll
                for (int pp = 0; pp < 8; ++pp) {
                    const int pq = ph * 8 + pp;
                    const float4 m = *(const float4*)(&mean_s[(pq * CC + c) * MPAD + dc * 4]);
                    acc2[pp].x = fmaf(m.x, w0.x, acc2[pp].x);
                    acc2[pp].y = fmaf(m.x, w0.y, acc2[pp].y);
                    acc2[pp].z = fmaf(m.x, w0.z, acc2[pp].z);
                    acc2[pp].w = fmaf(m.x, w0.w, acc2[pp].w);
                    acc2[pp].x = fmaf(m.y, w1.x, acc2[pp].x);
                    acc2[pp].y = fmaf(m.y, w1.y, acc2[pp].y);
                    acc2[pp].z = fmaf(m.y, w1.z, acc2[pp].z);
                    acc2[pp].w = fmaf(m.y, w1.w, acc2[pp].w);
                    acc2[pp].x = fmaf(m.z, w2.x, acc2[pp].x);
                    acc2[pp].y = fmaf(m.z, w2.y, acc2[pp].y);
                    acc2[pp].z = fmaf(m.z, w2.z, acc2[pp].z);
                    acc2[pp].w = fmaf(m.z, w2.w, acc2[pp].w);
                    acc2[pp].x = fmaf(m.w, w3.x, acc2[pp].x);
                    acc2[pp].y = fmaf(m.w, w3.y, acc2[pp].y);
                    acc2[pp].z = fmaf(m.w, w3.z, acc2[pp].z);
                    acc2[pp].w = fmaf(m.w, w3.w, acc2[pp].w);
                }
            }
        } else {
            // fallback: raw W layout (scattered within wave, works without d_ws)
            const float* __restrict__ Wc = W + (size_t)c * DOUT * DIN;
            #pragma unroll 1
            for (int dc = 0; dc < 16; ++dc) {
                float4 w[4];
                #pragma unroll
                for (int j = 0; j < 4; ++j)
                    w[j] = *(const float4*)(Wc + (size_t)(o0 + j) * DIN + dc * 4);
                #pragma unroll
                for (int pp = 0; pp < 8; ++pp) {
                    const int pq = ph * 8 + pp;
                    const float4 m = *(const float4*)(&mean_s[(pq * CC + c) * MPAD + dc * 4]);
                    float* a = (float*)&acc2[pp];
                    #pragma unroll
                    for (int j = 0; j < 4; ++j) {
                        a[j] = fmaf(m.x, w[j].x, a[j]);
                        a[j] = fmaf(m.y, w[j].y, a[j]);
                        a[j] = fmaf(m.z, w[j].z, a[j]);
                        a[j] = fmaf(m.w, w[j].w, a[j]);
                    }
                }
            }
        }

        #pragma unroll
        for (int pp = 0; pp < 8; ++pp) {
            const int pq = ph * 8 + pp;
            const int nn = n0 + pq;
            if (nn < NN) {
                float4 r;
                r.x = fast_tanh(acc2[pp].x);
                r.y = fast_tanh(acc2[pp].y);
                r.z = fast_tanh(acc2[pp].z);
                r.w = fast_tanh(acc2[pp].w);
                *(float4*)(out + (((size_t)(b * NN + nn)) * CC + c) * DOUT + o0) = r;
            }
        }
    }
}

extern "C" void kernel_launch(void* const* d_in, const int* in_sizes, int n_in,
                              void* d_out, int out_size, void* d_ws, size_t ws_size,
                              hipStream_t stream) {
    const int*   idx = (const int*)d_in[0];    // clustered_index_topk [B,N,K] int32
    const float* x   = (const float*)d_in[1];  // weightedDinput_topk [B,N,K,DIN] f32
    const float* W   = (const float*)d_in[2];  // W [C,DOUT,DIN] f32
    float* out = (float*)d_out;                // [B,N,C,DOUT] f32
    float* Wt  = (float*)d_ws;                 // [C,DIN,DOUT] scratch

    dim3 grid(NT, BB);   // 13 x 64 = 832 blocks
    dim3 block(256);
    const size_t wt_bytes = (size_t)CC * DIN * DOUT * sizeof(float);  // 128 KB
    if (ws_size >= wt_bytes) {
        transpose_W_kernel<<<dim3(CC), block, 0, stream>>>(W, Wt);
        ordered_gcn_kernel<true><<<grid, block, 0, stream>>>(idx, x, W, Wt, out);
    } else {
        ordered_gcn_kernel<false><<<grid, block, 0, stream>>>(idx, x, W, Wt, out);
    }
}